// Round 16
// baseline (3746.551 us; speedup 1.0000x reference)
//
#include <hip/hip_runtime.h>

#define DIM    128
#define HEADS  4
#define CH     32
#define MEMLEN 256
#define LAYERS 4

typedef unsigned int uint;
typedef unsigned short ushort;
using bf16x8 = __attribute__((ext_vector_type(8))) short;
using f32x4  = __attribute__((ext_vector_type(4))) float;

__device__ __forceinline__ ushort bf16_rn(float x) {
    uint u = __float_as_uint(x);
    uint r = (u + 0x7fffu + ((u >> 16) & 1u)) >> 16;
    return (ushort)r;
}
__device__ __forceinline__ void split_bf(float v, ushort& h, ushort& lo) {
    h = bf16_rn(v);
    float hf = __uint_as_float(((uint)h) << 16);
    lo = bf16_rn(v - hf);
}

// ---------------- utility ----------------

__global__ void copy_f4(const float4* __restrict__ in, float4* __restrict__ out, long n) {
    long i = (long)blockIdx.x * blockDim.x + threadIdx.x;
    long stride = (long)gridDim.x * blockDim.x;
    for (; i < n; i += stride) out[i] = in[i];
}

__global__ void hist_k(const int* __restrict__ dst, int E, int* __restrict__ deg) {
    int e = blockIdx.x * blockDim.x + threadIdx.x;
    if (e < E) atomicAdd(&deg[dst[e]], 1);
}

// one block, 1024 threads: exclusive scan of deg[0..n) -> off[0..n]
__global__ void csr_offsets(const int* __restrict__ deg, int n, int* __restrict__ off) {
    __shared__ int part[1024];
    int t = threadIdx.x;
    int chunk = (n + 1023) >> 10;
    int lo = t * chunk, hi = min(lo + chunk, n);
    int s = 0;
    for (int i = lo; i < hi; i++) s += deg[i];
    part[t] = s; __syncthreads();
    for (int d = 1; d < 1024; d <<= 1) {
        int v = part[t];
        int add = (t >= d) ? part[t - d] : 0;
        __syncthreads();
        part[t] = v + add;
        __syncthreads();
    }
    int run = (t == 0) ? 0 : part[t - 1];
    for (int i = lo; i < hi; i++) { off[i] = run; run += deg[i]; }
    if (t == 1023) off[n] = part[1023];
}

__global__ void csr_fill(const int* __restrict__ dst, int E, const int* __restrict__ off,
                         int* __restrict__ cur, int* __restrict__ csr) {
    int e = blockIdx.x * blockDim.x + threadIdx.x;
    if (e < E) {
        int d = dst[e];
        int p = atomicAdd(&cur[d], 1);
        csr[off[d] + p] = e;
    }
}

// ---------------- bf16 weight precompute (MFMA fragment order) ----------------
__global__ void make_w1f(const float* __restrict__ Ew1, ushort* __restrict__ W1f) {
    int i = blockIdx.x * 256 + threadIdx.x;
    if (i >= LAYERS * 12 * 8 * 64 * 8) return;
    int l = i / 49152; int r = i % 49152;
    int ks = r / 4096;  int r2 = r % 4096;
    int ct = r2 / 512;  int r3 = r2 % 512;
    int lane = r3 / 8;  int j = r3 % 8;
    int k = ks * 32 + (lane >> 4) * 8 + j;
    int n = (lane & 15) + 16 * ct;
    const float* W = Ew1 + (size_t)l * 3 * DIM * DIM;   // e-part rows 0..127
    float v = W[(size_t)(k % 128) * DIM + n];
    ushort h = bf16_rn(v);
    ushort out = h;
    if (k >= 256) {
        float hf = __uint_as_float(((uint)h) << 16);
        out = bf16_rn(v - hf);
    }
    W1f[i] = out;
}

__global__ void make_w2f(const float* __restrict__ Ew2, ushort* __restrict__ W2f) {
    int i = blockIdx.x * 256 + threadIdx.x;
    if (i >= LAYERS * 8 * 8 * 64 * 8) return;
    int l = i / 32768; int r = i % 32768;
    int ks = r / 4096;  int r2 = r % 4096;
    int ct = r2 / 512;  int r3 = r2 % 512;
    int lane = r3 / 8;  int j = r3 % 8;
    int k = ks * 32 + (lane >> 4) * 8 + j;
    int n = (lane & 15) + 16 * ct;
    const float* W = Ew2 + (size_t)l * DIM * DIM;
    W2f[i] = bf16_rn(W[(size_t)(k >> 1) * DIM + n]);
}

// ---------------- generic 64x128 fp32 tile GEMM: out = A@W (+bias) ----------------
__global__ __launch_bounds__(256) void gemm128(const float* __restrict__ A,
                                               const float* __restrict__ W,
                                               const float* __restrict__ bias,
                                               float* __restrict__ out, int R) {
    int r0 = blockIdx.x * 64, t = threadIdx.x;
    __shared__ float at[64][DIM];
    for (int i = t; i < 64 * 32; i += 256) {
        int rr = i >> 5, cc = i & 31;
        if (r0 + rr < R)
            ((float4*)at[rr])[cc] = ((const float4*)(A + (size_t)(r0 + rr) * DIM))[cc];
    }
    __syncthreads();
    int c0 = (t & 31) * 4;
    int rb = (t >> 5) * 8;
    float acc[8][4];
#pragma unroll
    for (int ee = 0; ee < 8; ee++)
        acc[ee][0] = acc[ee][1] = acc[ee][2] = acc[ee][3] = 0.f;
    for (int k = 0; k < DIM; k += 4) {
        float4 w0 = *(const float4*)&W[(k + 0) * DIM + c0];
        float4 w1 = *(const float4*)&W[(k + 1) * DIM + c0];
        float4 w2 = *(const float4*)&W[(k + 2) * DIM + c0];
        float4 w3 = *(const float4*)&W[(k + 3) * DIM + c0];
#pragma unroll
        for (int ee = 0; ee < 8; ee++) {
            float4 a = *(float4*)&at[rb + ee][k];
            acc[ee][0] += a.x * w0.x + a.y * w1.x + a.z * w2.x + a.w * w3.x;
            acc[ee][1] += a.x * w0.y + a.y * w1.y + a.z * w2.y + a.w * w3.y;
            acc[ee][2] += a.x * w0.z + a.y * w1.z + a.z * w2.z + a.w * w3.z;
            acc[ee][3] += a.x * w0.w + a.y * w1.w + a.z * w2.w + a.w * w3.w;
        }
    }
    float4 bb = make_float4(0.f, 0.f, 0.f, 0.f);
    if (bias) bb = *(const float4*)&bias[c0];
#pragma unroll
    for (int ee = 0; ee < 8; ee++) {
        int r = r0 + rb + ee;
        if (r < R) {
            float4 o = make_float4(acc[ee][0] + bb.x, acc[ee][1] + bb.y,
                                   acc[ee][2] + bb.z, acc[ee][3] + bb.w);
            *(float4*)&out[(size_t)r * DIM + c0] = o;
        }
    }
}

// ---------------- dual-output tile GEMM: outA = A@Wa (+biasA), outB = A@Wb ----------------
__global__ __launch_bounds__(256, 2) void gemm128_dual(const float* __restrict__ A,
                                                       const float* __restrict__ Wa,
                                                       const float* __restrict__ Wb,
                                                       const float* __restrict__ biasA,
                                                       float* __restrict__ outA,
                                                       float* __restrict__ outB, int R) {
    int r0 = blockIdx.x * 64, t = threadIdx.x;
    __shared__ float at[64][DIM];
    for (int i = t; i < 64 * 32; i += 256) {
        int rr = i >> 5, cc = i & 31;
        if (r0 + rr < R)
            ((float4*)at[rr])[cc] = ((const float4*)(A + (size_t)(r0 + rr) * DIM))[cc];
    }
    __syncthreads();
    int c0 = (t & 31) * 4;
    int rb = (t >> 5) * 8;
    float accA[8][4], accB[8][4];
#pragma unroll
    for (int ee = 0; ee < 8; ee++)
#pragma unroll
        for (int j = 0; j < 4; j++) { accA[ee][j] = 0.f; accB[ee][j] = 0.f; }
    for (int k = 0; k < DIM; k += 4) {
        float4 wa0 = *(const float4*)&Wa[(k + 0) * DIM + c0];
        float4 wa1 = *(const float4*)&Wa[(k + 1) * DIM + c0];
        float4 wa2 = *(const float4*)&Wa[(k + 2) * DIM + c0];
        float4 wa3 = *(const float4*)&Wa[(k + 3) * DIM + c0];
        float4 wb0 = *(const float4*)&Wb[(k + 0) * DIM + c0];
        float4 wb1 = *(const float4*)&Wb[(k + 1) * DIM + c0];
        float4 wb2 = *(const float4*)&Wb[(k + 2) * DIM + c0];
        float4 wb3 = *(const float4*)&Wb[(k + 3) * DIM + c0];
#pragma unroll
        for (int ee = 0; ee < 8; ee++) {
            float4 a = *(float4*)&at[rb + ee][k];
            accA[ee][0] += a.x * wa0.x + a.y * wa1.x + a.z * wa2.x + a.w * wa3.x;
            accA[ee][1] += a.x * wa0.y + a.y * wa1.y + a.z * wa2.y + a.w * wa3.y;
            accA[ee][2] += a.x * wa0.z + a.y * wa1.z + a.z * wa2.z + a.w * wa3.z;
            accA[ee][3] += a.x * wa0.w + a.y * wa1.w + a.z * wa2.w + a.w * wa3.w;
            accB[ee][0] += a.x * wb0.x + a.y * wb1.x + a.z * wb2.x + a.w * wb3.x;
            accB[ee][1] += a.x * wb0.y + a.y * wb1.y + a.z * wb2.y + a.w * wb3.y;
            accB[ee][2] += a.x * wb0.z + a.y * wb1.z + a.z * wb2.z + a.w * wb3.z;
            accB[ee][3] += a.x * wb0.w + a.y * wb1.w + a.z * wb2.w + a.w * wb3.w;
        }
    }
    float4 bb = make_float4(0.f, 0.f, 0.f, 0.f);
    if (biasA) bb = *(const float4*)&biasA[c0];
#pragma unroll
    for (int ee = 0; ee < 8; ee++) {
        int r = r0 + rb + ee;
        if (r < R) {
            *(float4*)&outA[(size_t)r * DIM + c0] =
                make_float4(accA[ee][0] + bb.x, accA[ee][1] + bb.y,
                            accA[ee][2] + bb.z, accA[ee][3] + bb.w);
            *(float4*)&outB[(size_t)r * DIM + c0] =
                make_float4(accB[ee][0], accB[ee][1], accB[ee][2], accB[ee][3]);
        }
    }
}

// ---------------- node proj tile: h = x@Wn, + per-head att dots ----------------
__global__ __launch_bounds__(256) void node_proj_tile(
    const float* __restrict__ x, const float* __restrict__ W,
    const float* __restrict__ att_s, const float* __restrict__ att_d,
    float* __restrict__ h, float* __restrict__ ssrc, float* __restrict__ sdst, int N) {
    int r0 = blockIdx.x * 64, t = threadIdx.x;
    __shared__ float at[64][DIM];
    for (int i = t; i < 64 * 32; i += 256) {
        int rr = i >> 5, cc = i & 31;
        if (r0 + rr < N)
            ((float4*)at[rr])[cc] = ((const float4*)(x + (size_t)(r0 + rr) * DIM))[cc];
    }
    __syncthreads();
    int c0 = (t & 31) * 4;
    int rb = (t >> 5) * 8;
    float acc[8][4];
#pragma unroll
    for (int ee = 0; ee < 8; ee++)
        acc[ee][0] = acc[ee][1] = acc[ee][2] = acc[ee][3] = 0.f;
    for (int k = 0; k < DIM; k += 4) {
        float4 w0 = *(const float4*)&W[(k + 0) * DIM + c0];
        float4 w1 = *(const float4*)&W[(k + 1) * DIM + c0];
        float4 w2 = *(const float4*)&W[(k + 2) * DIM + c0];
        float4 w3 = *(const float4*)&W[(k + 3) * DIM + c0];
#pragma unroll
        for (int ee = 0; ee < 8; ee++) {
            float4 a = *(float4*)&at[rb + ee][k];
            acc[ee][0] += a.x * w0.x + a.y * w1.x + a.z * w2.x + a.w * w3.x;
            acc[ee][1] += a.x * w0.y + a.y * w1.y + a.z * w2.y + a.w * w3.y;
            acc[ee][2] += a.x * w0.z + a.y * w1.z + a.z * w2.z + a.w * w3.z;
            acc[ee][3] += a.x * w0.w + a.y * w1.w + a.z * w2.w + a.w * w3.w;
        }
    }
    int hh = (t & 31) >> 3;   // head owned by this col range
    float4 as = *(const float4*)&att_s[c0];
    float4 ad = *(const float4*)&att_d[c0];
#pragma unroll
    for (int ee = 0; ee < 8; ee++) {
        int r = r0 + rb + ee;
        if (r < N) {
            *(float4*)&h[(size_t)r * DIM + c0] =
                make_float4(acc[ee][0], acc[ee][1], acc[ee][2], acc[ee][3]);
            float ps = acc[ee][0]*as.x + acc[ee][1]*as.y + acc[ee][2]*as.z + acc[ee][3]*as.w;
            float pd = acc[ee][0]*ad.x + acc[ee][1]*ad.y + acc[ee][2]*ad.z + acc[ee][3]*ad.w;
#pragma unroll
            for (int mk = 1; mk < 8; mk <<= 1) {
                ps += __shfl_xor(ps, mk, 32);
                pd += __shfl_xor(pd, mk, 32);
            }
            if (((t & 31) & 7) == 0) {
                ssrc[r * HEADS + hh] = ps;
                sdst[r * HEADS + hh] = pd;
            }
        }
    }
}

// ---------------- layer kernels ----------------

// waE[k][h] = sum_c We[k][h*32+c] * att_edge[h*32+c]   (1 block, 128 threads)
__global__ void make_waE(const float* __restrict__ We, const float* __restrict__ att_e,
                         float* __restrict__ waE) {
    int k = threadIdx.x;
#pragma unroll
    for (int h = 0; h < HEADS; h++) {
        float s = 0.f;
#pragma unroll
        for (int c = 0; c < CH; c++) s += We[k * DIM + h * CH + c] * att_e[h * CH + c];
        waE[k * HEADS + h] = s;
    }
}

// standalone logits for layer 0 only.
__global__ void sedge_logits(const float* __restrict__ e, const float* __restrict__ waE,
                             const float* __restrict__ ssrc, const float* __restrict__ sdst,
                             const int* __restrict__ src, const int* __restrict__ dst,
                             float* __restrict__ lw, int E) {
    __shared__ float w[DIM * HEADS];
    int t = threadIdx.x;
    w[t] = waE[t]; w[t + 256] = waE[t + 256];
    __syncthreads();
    int g = t >> 5, lane = t & 31;
    int eid = blockIdx.x * 8 + g;
    if (eid >= E) return;
    const float* er = e + (size_t)eid * DIM;
    float s0 = 0.f, s1 = 0.f, s2 = 0.f, s3 = 0.f;
#pragma unroll
    for (int j = 0; j < 4; j++) {
        int k = lane + 32 * j;
        float v = er[k];
        s0 += v * w[k * 4 + 0]; s1 += v * w[k * 4 + 1];
        s2 += v * w[k * 4 + 2]; s3 += v * w[k * 4 + 3];
    }
#pragma unroll
    for (int m = 16; m; m >>= 1) {
        s0 += __shfl_xor(s0, m, 32); s1 += __shfl_xor(s1, m, 32);
        s2 += __shfl_xor(s2, m, 32); s3 += __shfl_xor(s3, m, 32);
    }
    if (lane == 0) {
        int sn = src[eid] * HEADS, dn = dst[eid] * HEADS;
        float l0 = ssrc[sn + 0] + sdst[dn + 0] + s0;
        float l1 = ssrc[sn + 1] + sdst[dn + 1] + s1;
        float l2 = ssrc[sn + 2] + sdst[dn + 2] + s2;
        float l3 = ssrc[sn + 3] + sdst[dn + 3] + s3;
        lw[eid * 4 + 0] = (l0 >= 0.f) ? l0 : 0.2f * l0;
        lw[eid * 4 + 1] = (l1 >= 0.f) ? l1 : 0.2f * l1;
        lw[eid * 4 + 2] = (l2 >= 0.f) ? l2 : 0.2f * l2;
        lw[eid * 4 + 3] = (l3 >= 0.f) ? l3 : 0.2f * l3;
    }
}

// per (node, head) thread: segment max, exp, sum. lw becomes unnormalized weights.
__global__ void seg_softmax(const int* __restrict__ off, const int* __restrict__ csr,
                            float* __restrict__ lw, float* __restrict__ den, int NH) {
    int i = blockIdx.x * blockDim.x + threadIdx.x;
    if (i >= NH) return;
    int n = i >> 2, hh = i & 3;
    int o0 = off[n], o1 = off[n + 1];
    float m = -1e30f;
    for (int o = o0; o < o1; o++) m = fmaxf(m, lw[csr[o] * HEADS + hh]);
    float s = 0.f;
    for (int o = o0; o < o1; o++) {
        int idx = csr[o] * HEADS + hh;
        float w = __expf(lw[idx] - m);
        lw[idx] = w;
        s += w;
    }
    den[i] = s;
}

// conv gather, 4-way edge-parallel per node. 512 thr = 4 parts x 128 cols.
__global__ __launch_bounds__(512) void conv_ln4(
    const int* __restrict__ off, const int* __restrict__ csr, const int* __restrict__ src,
    const float* __restrict__ lw, const float* __restrict__ den,
    const float* __restrict__ hbuf, const float* __restrict__ e, const float* __restrict__ We,
    const float* __restrict__ bn, const float* __restrict__ g, const float* __restrict__ b,
    float* __restrict__ x, int N) {
    int t = threadIdx.x;
    int tt = t & 127, part = t >> 7;
    int n = blockIdx.x;
    int hh = tt >> 5;
    __shared__ float aggeP[4][HEADS][DIM];
    __shared__ float acchP[4][DIM];
    __shared__ float ehcP[4][DIM];
    __shared__ float wred[16];
    int o0 = off[n], o1 = off[n + 1];
    float acch = 0.f, a0 = 0.f, a1 = 0.f, a2 = 0.f, a3 = 0.f;
    for (int o = o0 + part; o < o1; o += 4) {
        int eid = csr[o];
        int s = src[eid];
        float4 al = *(const float4*)&lw[eid * 4];
        acch += ((&al.x)[hh]) * hbuf[(size_t)s * DIM + tt];
        float ev = e[(size_t)eid * DIM + tt];
        a0 += al.x * ev; a1 += al.y * ev; a2 += al.z * ev; a3 += al.w * ev;
    }
    aggeP[part][0][tt] = a0; aggeP[part][1][tt] = a1;
    aggeP[part][2][tt] = a2; aggeP[part][3][tt] = a3;
    acchP[part][tt] = acch;
    __syncthreads();
    float ehc = 0.f;
    int k0 = part * 32;
    for (int k = k0; k < k0 + 32; k++) {
        float ag = aggeP[0][hh][k] + aggeP[1][hh][k] + aggeP[2][hh][k] + aggeP[3][hh][k];
        ehc += ag * We[k * DIM + tt];
    }
    ehcP[part][tt] = ehc;
    __syncthreads();
    float conv = (acchP[0][tt] + acchP[1][tt] + acchP[2][tt] + acchP[3][tt]
                + ehcP[0][tt] + ehcP[1][tt] + ehcP[2][tt] + ehcP[3][tt])
                 / (den[n * HEADS + hh] + 1e-16f) + bn[tt];
    int w = t >> 6;
    float s1 = conv;
#pragma unroll
    for (int mk = 32; mk; mk >>= 1) s1 += __shfl_xor(s1, mk, 64);
    if ((t & 63) == 0) wred[w] = s1;
    __syncthreads();
    float mu = (wred[w] + wred[w ^ 1]) * (1.f / DIM);
    float diff = conv - mu;
    float s2 = diff * diff;
#pragma unroll
    for (int mk = 32; mk; mk >>= 1) s2 += __shfl_xor(s2, mk, 64);
    if ((t & 63) == 0) wred[8 + w] = s2;
    __syncthreads();
    float var = (wred[8 + w] + wred[8 + (w ^ 1)]) * (1.f / DIM);
    if (part == 0) {
        float y = diff * rsqrtf(var + 1e-5f) * g[tt] + b[tt];
        x[(size_t)n * DIM + tt] = fmaxf(y, 0.f) + x[(size_t)n * DIM + tt];
    }
}

// flash-style cross attention: 64 queries x 1 batch per block, 256 thr = 64q x 4h.
__global__ __launch_bounds__(256) void cross_attn_tile(
    float* __restrict__ x, const float* __restrict__ qg,
    const float* __restrict__ kb, const float* __restrict__ vb,
    const float* __restrict__ Wo, const float* __restrict__ g,
    const float* __restrict__ b, const int* __restrict__ boff) {
    int bb = blockIdx.y;
    int n0 = boff[bb] + blockIdx.x * 64;
    int cnt = boff[bb + 1] - n0;
    if (cnt <= 0) return;
    int nq = min(64, cnt);
    int t = threadIdx.x;
    int q = t & 63, h = t >> 6;

    __shared__ float smem[64 * 132];

    float qv[32];
    if (q < nq) {
        const float4* qp = (const float4*)(qg + (size_t)(n0 + q) * DIM + h * CH);
#pragma unroll
        for (int j = 0; j < 8; j++) {
            float4 v = qp[j];
            qv[4*j+0] = v.x; qv[4*j+1] = v.y; qv[4*j+2] = v.z; qv[4*j+3] = v.w;
        }
    } else {
#pragma unroll
        for (int c = 0; c < 32; c++) qv[c] = 0.f;
    }

    float oacc[32];
#pragma unroll
    for (int c = 0; c < 32; c++) oacc[c] = 0.f;
    float m = -1e30f, l = 0.f;

    const float4* Ksrc = (const float4*)(kb + (size_t)bb * MEMLEN * DIM);
    const float4* Vsrc = (const float4*)(vb + (size_t)bb * MEMLEN * DIM);
    float4* Kl = (float4*)smem;
    float4* Vl = (float4*)(smem + 32 * DIM);

    for (int ch = 0; ch < MEMLEN / 32; ch++) {
        __syncthreads();
#pragma unroll
        for (int r = 0; r < 4; r++) {
            int idx = t + r * 256;
            Kl[idx] = Ksrc[ch * 1024 + idx];
            Vl[idx] = Vsrc[ch * 1024 + idx];
        }
        __syncthreads();
        float sc[32];
#pragma unroll
        for (int kk = 0; kk < 32; kk++) {
            const float* kp = smem + kk * DIM + h * CH;
            float s = 0.f;
#pragma unroll
            for (int c = 0; c < 32; c++) s += qv[c] * kp[c];
            sc[kk] = s * 0.17677669529663689f;
        }
        float mc = sc[0];
#pragma unroll
        for (int kk = 1; kk < 32; kk++) mc = fmaxf(mc, sc[kk]);
        float mn = fmaxf(m, mc);
        float scale = __expf(m - mn);
        m = mn;
        float ls = 0.f;
#pragma unroll
        for (int kk = 0; kk < 32; kk++) {
            float w = __expf(sc[kk] - mn);
            sc[kk] = w;
            ls += w;
        }
        l = l * scale + ls;
#pragma unroll
        for (int c = 0; c < 32; c++) oacc[c] *= scale;
#pragma unroll
        for (int kk = 0; kk < 32; kk++) {
            const float* vp = smem + 32 * DIM + kk * DIM + h * CH;
            float w = sc[kk];
#pragma unroll
            for (int c = 0; c < 32; c++) oacc[c] += w * vp[c];
        }
    }
    __syncthreads();
    {
        float inv = 1.f / l;
        float* ap = smem + q * 132 + h * CH;
#pragma unroll
        for (int c = 0; c < 32; c++) ap[c] = oacc[c] * inv;
    }
    __syncthreads();
    int c0 = (t & 31) * 4;
    int rb = (t >> 5) * 8;
    float acc2[8][4];
#pragma unroll
    for (int ee = 0; ee < 8; ee++)
        acc2[ee][0] = acc2[ee][1] = acc2[ee][2] = acc2[ee][3] = 0.f;
    for (int k = 0; k < DIM; k += 4) {
        float4 w0 = *(const float4*)&Wo[(k + 0) * DIM + c0];
        float4 w1 = *(const float4*)&Wo[(k + 1) * DIM + c0];
        float4 w2 = *(const float4*)&Wo[(k + 2) * DIM + c0];
        float4 w3 = *(const float4*)&Wo[(k + 3) * DIM + c0];
#pragma unroll
        for (int ee = 0; ee < 8; ee++) {
            float4 a = *(const float4*)(smem + (rb + ee) * 132 + k);
            acc2[ee][0] += a.x * w0.x + a.y * w1.x + a.z * w2.x + a.w * w3.x;
            acc2[ee][1] += a.x * w0.y + a.y * w1.y + a.z * w2.y + a.w * w3.y;
            acc2[ee][2] += a.x * w0.z + a.y * w1.z + a.z * w2.z + a.w * w3.z;
            acc2[ee][3] += a.x * w0.w + a.y * w1.w + a.z * w2.w + a.w * w3.w;
        }
    }
    float4 gg = *(const float4*)&g[c0];
    float4 bb4 = *(const float4*)&b[c0];
#pragma unroll
    for (int ee = 0; ee < 8; ee++) {
        int r = rb + ee;
        if (r < nq) {
            float4 xr = *(const float4*)&x[(size_t)(n0 + r) * DIM + c0];
            float o0 = acc2[ee][0] + xr.x, o1 = acc2[ee][1] + xr.y;
            float o2 = acc2[ee][2] + xr.z, o3 = acc2[ee][3] + xr.w;
            float s1 = o0 + o1 + o2 + o3;
#pragma unroll
            for (int mk = 16; mk; mk >>= 1) s1 += __shfl_xor(s1, mk, 32);
            float mu = s1 * (1.f / DIM);
            float d0 = o0 - mu, d1 = o1 - mu, d2 = o2 - mu, d3 = o3 - mu;
            float s2 = d0*d0 + d1*d1 + d2*d2 + d3*d3;
#pragma unroll
            for (int mk = 16; mk; mk >>= 1) s2 += __shfl_xor(s2, mk, 32);
            float rs = rsqrtf(s2 * (1.f / DIM) + 1e-5f);
            float4 o = make_float4(fmaxf(d0 * rs * gg.x + bb4.x, 0.f),
                                   fmaxf(d1 * rs * gg.y + bb4.y, 0.f),
                                   fmaxf(d2 * rs * gg.z + bb4.z, 0.f),
                                   fmaxf(d3 * rs * gg.w + bb4.w, 0.f));
            *(float4*)&x[(size_t)(n0 + r) * DIM + c0] = o;
        }
    }
}

// ---------------- MFMA edge MLP v9 (v8 + 1-deep B prefetch to cut reg pressure) ----------------
// launch_bounds MUST stay (256,2): tighter caps spill catastrophically (R10/R14).
// B fragments now double-buffered 1-deep (live B regs 96 -> ~16) to raise occupancy.
__global__ __launch_bounds__(256, 2) void edge_mlp_mfma(
    float* __restrict__ e, const float* __restrict__ xs, const float* __restrict__ xd,
    const int* __restrict__ src, const int* __restrict__ dst,
    const ushort* __restrict__ W1f,   // [12 ks][8 ct][64 lane][8 j] bf16
    const ushort* __restrict__ W2f,   // [8 ks][8 ct][64 lane][8 j] bf16
    const float* __restrict__ Eb2,
    const float* __restrict__ waE,    // [128][4], next layer (or null)
    const float* __restrict__ ssrc, const float* __restrict__ sdst,
    float* __restrict__ lw, int doLogits, int E) {
    __shared__ __align__(16) char smemraw[64 * 132 * 4];  // As (bf16) then Af (fp32 padded)
    ushort* As = (ushort*)smemraw;
    float*  Af = (float*)smemraw;
    __shared__ float waEl[DIM * HEADS];
    int t = threadIdx.x;
    int e0 = blockIdx.x * 64;

    if (doLogits) {
        waEl[t] = waE[t];
        waEl[t + 256] = waE[t + 256];
    }

    int l = t & 63, wid = t >> 6;
    int g = l >> 4;
    int lr = l & 15;
    int ct0 = 2 * wid, ct1 = 2 * wid + 1;
    int col0 = lr + 16 * ct0, col1 = lr + 16 * ct1;

    // T14 early-issue: xs/xd gathers overlap staging + phase-1 MFMAs
    float xsd0[16], xsd1[16];
#pragma unroll
    for (int r = 0; r < 4; r++) {
#pragma unroll
        for (int j = 0; j < 4; j++) {
            int grow = e0 + r * 16 + g * 4 + j;
            int idx = r * 4 + j;
            if (grow < E) {
                int s = src[grow], d = dst[grow];
                xsd0[idx] = xs[(size_t)s * DIM + col0] + xd[(size_t)d * DIM + col0];
                xsd1[idx] = xs[(size_t)s * DIM + col1] + xd[(size_t)d * DIM + col1];
            } else {
                xsd0[idx] = 0.f; xsd1[idx] = 0.f;
            }
        }
    }

    // stage e-tile -> bf16 hi (k 0..127) + lo (k 128..255), swizzled
#pragma unroll
    for (int it = 0; it < 8; it++) {
        int i = t + it * 256;
        int row = i >> 5, c4 = i & 31;
        float4 v;
        if (e0 + row < E) v = *(const float4*)&e[(size_t)(e0 + row) * DIM + c4 * 4];
        else v = make_float4(0.f, 0.f, 0.f, 0.f);
        ushort h0, l0, h1, l1, h2, l2, h3, l3;
        split_bf(v.x, h0, l0); split_bf(v.y, h1, l1);
        split_bf(v.z, h2, l2); split_bf(v.w, h3, l3);
        int k = c4 * 4;
        int off = k & 7;
        int kbh = (k >> 3) ^ (row & 7);
        int kbl = ((128 + k) >> 3) ^ (row & 7);
        uint2 hw, lw2;
        hw.x = (uint)h0 | ((uint)h1 << 16); hw.y = (uint)h2 | ((uint)h3 << 16);
        lw2.x = (uint)l0 | ((uint)l1 << 16); lw2.y = (uint)l2 | ((uint)l3 << 16);
        *(uint2*)&As[row * 256 + kbh * 8 + off] = hw;
        *(uint2*)&As[row * 256 + kbl * 8 + off] = lw2;
    }

    // phase-1 B fragment prefetch (1-deep; live B = 2 pairs, not 12)
    const ushort* W1base = W1f + (size_t)ct0 * 512 + (size_t)l * 8;   // +512 for ct1
    bf16x8 bp0 = *(const bf16x8*)(W1base);
    bf16x8 bp1 = *(const bf16x8*)(W1base + 512);

    __syncthreads();   // A staged (+ waEl)

    f32x4 acc[4][2];
#pragma unroll
    for (int r = 0; r < 4; r++) {
        acc[r][0] = (f32x4){0.f, 0.f, 0.f, 0.f};
        acc[r][1] = (f32x4){0.f, 0.f, 0.f, 0.f};
    }

    // phase 1: K = 384, B prefetched 1 k-step ahead
#pragma unroll
    for (int ks = 0; ks < 12; ks++) {
        bf16x8 bc0 = bp0, bc1 = bp1;
        if (ks + 1 < 12) {
            bp0 = *(const bf16x8*)(W1base + (size_t)(ks + 1) * 4096);
            bp1 = *(const bf16x8*)(W1base + (size_t)(ks + 1) * 4096 + 512);
        }
        int ksA = (ks < 8) ? ks : (ks - 8);
#pragma unroll
        for (int r = 0; r < 4; r++) {
            int arow = r * 16 + lr;
            int kbm = (ksA * 4 + g) ^ (arow & 7);
            bf16x8 af = *(bf16x8*)&As[arow * 256 + kbm * 8];
            acc[r][0] = __builtin_amdgcn_mfma_f32_16x16x32_bf16(af, bc0, acc[r][0], 0, 0, 0);
            acc[r][1] = __builtin_amdgcn_mfma_f32_16x16x32_bf16(af, bc1, acc[r][1], 0, 0, 0);
        }
    }

    // prefetch first phase-2 B fragments (covers epilogue latency)
    const ushort* W2base = W2f + (size_t)ct0 * 512 + (size_t)l * 8;
    bp0 = *(const bf16x8*)(W2base);
    bp1 = *(const bf16x8*)(W2base + 512);

    __syncthreads();   // RACE FIX: all waves' phase-1 As reads complete before hid writes

    // phase-1 epilogue: + xsd (preloaded), relu, split -> hid into As
    int kb0 = col0 >> 2, off0 = (2 * col0) & 7;
    int kb1 = col1 >> 2, off1 = (2 * col1) & 7;
#pragma unroll
    for (int r = 0; r < 4; r++) {
#pragma unroll
        for (int j = 0; j < 4; j++) {
            int rowloc = r * 16 + g * 4 + j;
            float v0 = fmaxf(acc[r][0][j] + xsd0[r * 4 + j], 0.f);
            float v1 = fmaxf(acc[r][1][j] + xsd1[r * 4 + j], 0.f);
            ushort h0s, l0s, h1s, l1s;
            split_bf(v0, h0s, l0s);
            split_bf(v1, h1s, l1s);
            int rs = rowloc & 7;
            *(uint*)&As[rowloc * 256 + (kb0 ^ rs) * 8 + off0] = (uint)h0s | ((uint)l0s << 16);
            *(uint*)&As[rowloc * 256 + (kb1 ^ rs) * 8 + off1] = (uint)h1s | ((uint)l1s << 16);
        }
    }
    __syncthreads();   // hid complete across all waves

    // phase 2: K = 256, B prefetched 1 k-step ahead
    f32x4 acc2[4][2];
#pragma unroll
    for (int r = 0; r < 4; r++) {
        acc2[r][0] = (f32x4){0.f, 0.f, 0.f, 0.f};
        acc2[r][1] = (f32x4){0.f, 0.f, 0.f, 0.f};
    }
#pragma unroll
    for (int ks = 0; ks < 8; ks++) {
        bf16x8 bc0 = bp0, bc1 = bp1;
        if (ks + 1 < 8) {
            bp0 = *(const bf16x8*)(W2base + (size_t)(ks + 1) * 4096);
            bp1 = *(const bf16x8*)(W2base + (size_t)(ks + 1) * 4096 + 512);
        }
#pragma unroll
        for (int r = 0; r < 4; r++) {
            int arow = r * 16 + lr;
            int kbm = (ks * 4 + g) ^ (arow & 7);
            bf16x8 af = *(bf16x8*)&As[arow * 256 + kbm * 8];
            acc2[r][0] = __builtin_amdgcn_mfma_f32_16x16x32_bf16(af, bc0, acc2[r][0], 0, 0, 0);
            acc2[r][1] = __builtin_amdgcn_mfma_f32_16x16x32_bf16(af, bc1, acc2[r][1], 0, 0, 0);
        }
    }
    __syncthreads();   // hid reads done; As dead -> reuse as Af[64][132]

    // epilogue 2a: Af = acc2 + Eb2
    float b20 = Eb2[col0], b21 = Eb2[col1];
#pragma unroll
    for (int r = 0; r < 4; r++) {
#pragma unroll
        for (int j = 0; j < 4; j++) {
            int rowloc = r * 16 + g * 4 + j;
            Af[rowloc * 132 + col0] = acc2[r][0][j] + b20;
            Af[rowloc * 132 + col1] = acc2[r][1][j] + b21;
        }
    }
    __syncthreads();

    // epilogue 2b: coalesced float4 RMW of e; save final values back into Af
#pragma unroll
    for (int it = 0; it < 8; it++) {
        int i = t + it * 256;
        int row = i >> 5, c4 = i & 31;
        int grow = e0 + row;
        if (grow < E) {
            float4 ev = *(const float4*)&e[(size_t)grow * DIM + c4 * 4];
            float* ap = &Af[row * 132 + c4 * 4];
            ev.x += ap[0]; ev.y += ap[1]; ev.z += ap[2]; ev.w += ap[3];
            *(float4*)&e[(size_t)grow * DIM + c4 * 4] = ev;
            ap[0] = ev.x; ap[1] = ev.y; ap[2] = ev.z; ap[3] = ev.w;
        }
    }

    // fused next-layer logits (raw leaky logits; seg_softmax normalizes later)
    if (doLogits) {
        __syncthreads();
        int row = t >> 2, h = t & 3;
        int grow = e0 + row;
        if (grow < E) {
            const float* ar = &Af[row * 132];
            float s = 0.f;
#pragma unroll 8
            for (int k = 0; k < DIM; k++) s += ar[k] * waEl[k * 4 + h];
            s += ssrc[src[grow] * HEADS + h] + sdst[dst[grow] * HEADS + h];
            lw[grow * 4 + h] = (s >= 0.f) ? s : 0.2f * s;
        }
    }
}

// ---------------- driver ----------------

extern "C" void kernel_launch(void* const* d_in, const int* in_sizes, int n_in,
                              void* d_out, int out_size, void* d_ws, size_t ws_size,
                              hipStream_t stream) {
    const float* node_feats = (const float*)d_in[0];
    const float* edge_feats = (const float*)d_in[1];
    const float* memory     = (const float*)d_in[2];
    const float* Wn   = (const float*)d_in[3];
    const float* bn   = (const float*)d_in[4];
    const float* We   = (const float*)d_in[5];
    const float* att_src  = (const float*)d_in[6];
    const float* att_dst  = (const float*)d_in[7];
    const float* att_edge = (const float*)d_in[8];
    const float* ln1_g = (const float*)d_in[9];
    const float* ln1_b = (const float*)d_in[10];
    const float* ln2_g = (const float*)d_in[11];
    const float* ln2_b = (const float*)d_in[12];
    const float* Wq = (const float*)d_in[13];
    const float* Wk = (const float*)d_in[14];
    const float* Wv = (const float*)d_in[15];
    const float* Wo = (const float*)d_in[16];
    const float* Ew1 = (const float*)d_in[17];
    const float* Eb1 = (const float*)d_in[18];
    const float* Ew2 = (const float*)d_in[19];
    const float* Eb2 = (const float*)d_in[20];
    const int* edge_index = (const int*)d_in[21];
    const int* node2batch = (const int*)d_in[22];

    const int N = in_sizes[0] / DIM;
    const int E = in_sizes[1] / DIM;
    const int Bn = in_sizes[2] / (MEMLEN * DIM);
    const int* srcA = edge_index;
    const int* dstA = edge_index + E;

    float* x = (float*)d_out;
    float* e = x + (size_t)N * DIM;

    // workspace carve
    char* p = (char*)d_ws;
    auto carve = [&](size_t bytes) {
        void* r = (void*)p;
        p += (bytes + 255) & ~(size_t)255;
        return r;
    };
    float* h     = (float*)carve((size_t)N * DIM * 4);
    float* qg    = (float*)carve((size_t)N * DIM * 4);
    float* xs    = (float*)carve((size_t)N * DIM * 4);
    float* xd    = (float*)carve((size_t)N * DIM * 4);
    float* ssrc  = (float*)carve((size_t)N * HEADS * 4);
    float* sdst  = (float*)carve((size_t)N * HEADS * 4);
    float* lw    = (float*)carve((size_t)E * HEADS * 4);
    float* den   = (float*)carve((size_t)N * HEADS * 4);
    float* waE   = (float*)carve((size_t)DIM * HEADS * 4);
    float* kbuf  = (float*)carve((size_t)Bn * MEMLEN * DIM * 4);
    float* vbuf  = (float*)carve((size_t)Bn * MEMLEN * DIM * 4);
    ushort* W1f  = (ushort*)carve((size_t)LAYERS * 12 * 4096 * 2);
    ushort* W2f  = (ushort*)carve((size_t)LAYERS * 8 * 4096 * 2);
    int* deg     = (int*)carve((size_t)N * 4);
    int* cur     = (int*)carve((size_t)N * 4);
    int* off     = (int*)carve(((size_t)N + 1) * 4);
    int* csr     = (int*)carve((size_t)E * 4);
    int* bcnt    = (int*)carve((size_t)Bn * 4);
    int* boff    = (int*)carve(((size_t)Bn + 1) * 4);

    // init outputs from inputs
    {
        long nx = (long)N * DIM / 4;
        copy_f4<<<dim3(2048), dim3(256), 0, stream>>>((const float4*)node_feats, (float4*)x, nx);
        long nen = (long)E * DIM / 4;
        copy_f4<<<dim3(4096), dim3(256), 0, stream>>>((const float4*)edge_feats, (float4*)e, nen);
    }

    // bf16 fragment-order weights (all layers, once)
    make_w1f<<<dim3((LAYERS * 49152 + 255) / 256), dim3(256), 0, stream>>>(Ew1, W1f);
    make_w2f<<<dim3((LAYERS * 32768 + 255) / 256), dim3(256), 0, stream>>>(Ew2, W2f);

    // CSR over dst + per-batch node offsets
    hipMemsetAsync(deg, 0, (size_t)N * 4, stream);
    hipMemsetAsync(cur, 0, (size_t)N * 4, stream);
    hipMemsetAsync(bcnt, 0, (size_t)Bn * 4, stream);
    hist_k<<<dim3((E + 255) / 256), dim3(256), 0, stream>>>(dstA, E, deg);
    csr_offsets<<<dim3(1), dim3(1024), 0, stream>>>(deg, N, off);
    csr_fill<<<dim3((E + 255) / 256), dim3(256), 0, stream>>>(dstA, E, off, cur, csr);
    hist_k<<<dim3((N + 255) / 256), dim3(256), 0, stream>>>(node2batch, N, bcnt);
    csr_offsets<<<dim3(1), dim3(1024), 0, stream>>>(bcnt, Bn, boff);

    const int mrows = Bn * MEMLEN;
    const int maxTiles = 1024 / 64;  // MAX_NODE / 64

    // layer-0 logits (standalone): needs node_proj(0) + waE(0)
    node_proj_tile<<<dim3((N + 63) / 64), dim3(256), 0, stream>>>(
        x, Wn, att_src, att_dst, h, ssrc, sdst, N);
    make_waE<<<dim3(1), dim3(DIM), 0, stream>>>(We, att_edge, waE);
    sedge_logits<<<dim3((E + 7) / 8), dim3(256), 0, stream>>>(
        e, waE, ssrc, sdst, srcA, dstA, lw, E);

    for (int l = 0; l < LAYERS; l++) {
        const float* We_l  = We  + (size_t)l * DIM * DIM;
        const float* Wq_l  = Wq  + (size_t)l * DIM * DIM;
        const float* Wo_l  = Wo  + (size_t)l * DIM * DIM;
        const float* Wk_l  = Wk  + (size_t)l * DIM * DIM;
        const float* Wv_l  = Wv  + (size_t)l * DIM * DIM;
        const float* Ew1_l = Ew1 + (size_t)l * 3 * DIM * DIM;

        seg_softmax<<<dim3((N * HEADS + 255) / 256), dim3(256), 0, stream>>>(
            off, csr, lw, den, N * HEADS);
        conv_ln4<<<dim3(N), dim3(512), 0, stream>>>(
            off, csr, srcA, lw, den, h, e, We_l,
            bn + l * DIM, ln1_g + l * DIM, ln1_b + l * DIM, x, N);
        gemm128_dual<<<dim3((mrows + 63) / 64), dim3(256), 0, stream>>>(
            memory, Wk_l, Wv_l, nullptr, kbuf, vbuf, mrows);
        gemm128<<<dim3((N + 63) / 64), dim3(256), 0, stream>>>(
            x, Wq_l, nullptr, qg, N);
        cross_attn_tile<<<dim3(maxTiles, Bn), dim3(256), 0, stream>>>(
            x, qg, kbuf, vbuf, Wo_l, ln2_g + l * DIM, ln2_b + l * DIM, boff);
        gemm128_dual<<<dim3((N + 63) / 64), dim3(256), 0, stream>>>(
            x, Ew1_l + (size_t)DIM * DIM, Ew1_l + (size_t)2 * DIM * DIM,
            Eb1 + l * DIM, xs, xd, N);

        if (l + 1 < LAYERS) {
            node_proj_tile<<<dim3((N + 63) / 64), dim3(256), 0, stream>>>(
                x, Wn + (size_t)(l + 1) * DIM * DIM,
                att_src + (l + 1) * DIM, att_dst + (l + 1) * DIM, h, ssrc, sdst, N);
            make_waE<<<dim3(1), dim3(DIM), 0, stream>>>(
                We + (size_t)(l + 1) * DIM * DIM, att_edge + (l + 1) * DIM, waE);
            edge_mlp_mfma<<<dim3((E + 63) / 64), dim3(256), 0, stream>>>(
                e, xs, xd, srcA, dstA,
                W1f + (size_t)l * 12 * 4096, W2f + (size_t)l * 8 * 4096,
                Eb2 + l * DIM, waE, ssrc, sdst, lw, 1, E);
        } else {
            edge_mlp_mfma<<<dim3((E + 63) / 64), dim3(256), 0, stream>>>(
                e, xs, xd, srcA, dstA,
                W1f + (size_t)l * 12 * 4096, W2f + (size_t)l * 8 * 4096,
                Eb2 + l * DIM, nullptr, nullptr, nullptr, nullptr, 0, E);
        }
    }
}

// Round 17
// 3643.939 us; speedup vs baseline: 1.0282x; 1.0282x over previous
//
#include <hip/hip_runtime.h>

#define DIM    128
#define HEADS  4
#define CH     32
#define MEMLEN 256
#define LAYERS 4

typedef unsigned int uint;
typedef unsigned short ushort;
using bf16x8 = __attribute__((ext_vector_type(8))) short;
using f32x4  = __attribute__((ext_vector_type(4))) float;

__device__ __forceinline__ ushort bf16_rn(float x) {
    uint u = __float_as_uint(x);
    uint r = (u + 0x7fffu + ((u >> 16) & 1u)) >> 16;
    return (ushort)r;
}
__device__ __forceinline__ void split_bf(float v, ushort& h, ushort& lo) {
    h = bf16_rn(v);
    float hf = __uint_as_float(((uint)h) << 16);
    lo = bf16_rn(v - hf);
}

// ---------------- utility ----------------

__global__ void copy_f4(const float4* __restrict__ in, float4* __restrict__ out, long n) {
    long i = (long)blockIdx.x * blockDim.x + threadIdx.x;
    long stride = (long)gridDim.x * blockDim.x;
    for (; i < n; i += stride) out[i] = in[i];
}

__global__ void hist_k(const int* __restrict__ dst, int E, int* __restrict__ deg) {
    int e = blockIdx.x * blockDim.x + threadIdx.x;
    if (e < E) atomicAdd(&deg[dst[e]], 1);
}

// one block, 1024 threads: exclusive scan of deg[0..n) -> off[0..n]
__global__ void csr_offsets(const int* __restrict__ deg, int n, int* __restrict__ off) {
    __shared__ int part[1024];
    int t = threadIdx.x;
    int chunk = (n + 1023) >> 10;
    int lo = t * chunk, hi = min(lo + chunk, n);
    int s = 0;
    for (int i = lo; i < hi; i++) s += deg[i];
    part[t] = s; __syncthreads();
    for (int d = 1; d < 1024; d <<= 1) {
        int v = part[t];
        int add = (t >= d) ? part[t - d] : 0;
        __syncthreads();
        part[t] = v + add;
        __syncthreads();
    }
    int run = (t == 0) ? 0 : part[t - 1];
    for (int i = lo; i < hi; i++) { off[i] = run; run += deg[i]; }
    if (t == 1023) off[n] = part[1023];
}

__global__ void csr_fill(const int* __restrict__ dst, int E, const int* __restrict__ off,
                         int* __restrict__ cur, int* __restrict__ csr) {
    int e = blockIdx.x * blockDim.x + threadIdx.x;
    if (e < E) {
        int d = dst[e];
        int p = atomicAdd(&cur[d], 1);
        csr[off[d] + p] = e;
    }
}

// ---------------- bf16 weight precompute (MFMA fragment order) ----------------
__global__ void make_w1f(const float* __restrict__ Ew1, ushort* __restrict__ W1f) {
    int i = blockIdx.x * 256 + threadIdx.x;
    if (i >= LAYERS * 12 * 8 * 64 * 8) return;
    int l = i / 49152; int r = i % 49152;
    int ks = r / 4096;  int r2 = r % 4096;
    int ct = r2 / 512;  int r3 = r2 % 512;
    int lane = r3 / 8;  int j = r3 % 8;
    int k = ks * 32 + (lane >> 4) * 8 + j;
    int n = (lane & 15) + 16 * ct;
    const float* W = Ew1 + (size_t)l * 3 * DIM * DIM;   // e-part rows 0..127
    float v = W[(size_t)(k % 128) * DIM + n];
    ushort h = bf16_rn(v);
    ushort out = h;
    if (k >= 256) {
        float hf = __uint_as_float(((uint)h) << 16);
        out = bf16_rn(v - hf);
    }
    W1f[i] = out;
}

__global__ void make_w2f(const float* __restrict__ Ew2, ushort* __restrict__ W2f) {
    int i = blockIdx.x * 256 + threadIdx.x;
    if (i >= LAYERS * 8 * 8 * 64 * 8) return;
    int l = i / 32768; int r = i % 32768;
    int ks = r / 4096;  int r2 = r % 4096;
    int ct = r2 / 512;  int r3 = r2 % 512;
    int lane = r3 / 8;  int j = r3 % 8;
    int k = ks * 32 + (lane >> 4) * 8 + j;
    int n = (lane & 15) + 16 * ct;
    const float* W = Ew2 + (size_t)l * DIM * DIM;
    W2f[i] = bf16_rn(W[(size_t)(k >> 1) * DIM + n]);
}

// ---------------- generic 64x128 fp32 tile GEMM: out = A@W (+bias) ----------------
__global__ __launch_bounds__(256) void gemm128(const float* __restrict__ A,
                                               const float* __restrict__ W,
                                               const float* __restrict__ bias,
                                               float* __restrict__ out, int R) {
    int r0 = blockIdx.x * 64, t = threadIdx.x;
    __shared__ float at[64][DIM];
    for (int i = t; i < 64 * 32; i += 256) {
        int rr = i >> 5, cc = i & 31;
        if (r0 + rr < R)
            ((float4*)at[rr])[cc] = ((const float4*)(A + (size_t)(r0 + rr) * DIM))[cc];
    }
    __syncthreads();
    int c0 = (t & 31) * 4;
    int rb = (t >> 5) * 8;
    float acc[8][4];
#pragma unroll
    for (int ee = 0; ee < 8; ee++)
        acc[ee][0] = acc[ee][1] = acc[ee][2] = acc[ee][3] = 0.f;
    for (int k = 0; k < DIM; k += 4) {
        float4 w0 = *(const float4*)&W[(k + 0) * DIM + c0];
        float4 w1 = *(const float4*)&W[(k + 1) * DIM + c0];
        float4 w2 = *(const float4*)&W[(k + 2) * DIM + c0];
        float4 w3 = *(const float4*)&W[(k + 3) * DIM + c0];
#pragma unroll
        for (int ee = 0; ee < 8; ee++) {
            float4 a = *(float4*)&at[rb + ee][k];
            acc[ee][0] += a.x * w0.x + a.y * w1.x + a.z * w2.x + a.w * w3.x;
            acc[ee][1] += a.x * w0.y + a.y * w1.y + a.z * w2.y + a.w * w3.y;
            acc[ee][2] += a.x * w0.z + a.y * w1.z + a.z * w2.z + a.w * w3.z;
            acc[ee][3] += a.x * w0.w + a.y * w1.w + a.z * w2.w + a.w * w3.w;
        }
    }
    float4 bb = make_float4(0.f, 0.f, 0.f, 0.f);
    if (bias) bb = *(const float4*)&bias[c0];
#pragma unroll
    for (int ee = 0; ee < 8; ee++) {
        int r = r0 + rb + ee;
        if (r < R) {
            float4 o = make_float4(acc[ee][0] + bb.x, acc[ee][1] + bb.y,
                                   acc[ee][2] + bb.z, acc[ee][3] + bb.w);
            *(float4*)&out[(size_t)r * DIM + c0] = o;
        }
    }
}

// ---------------- dual-output tile GEMM: outA = A@Wa (+biasA), outB = A@Wb ----------------
__global__ __launch_bounds__(256, 2) void gemm128_dual(const float* __restrict__ A,
                                                       const float* __restrict__ Wa,
                                                       const float* __restrict__ Wb,
                                                       const float* __restrict__ biasA,
                                                       float* __restrict__ outA,
                                                       float* __restrict__ outB, int R) {
    int r0 = blockIdx.x * 64, t = threadIdx.x;
    __shared__ float at[64][DIM];
    for (int i = t; i < 64 * 32; i += 256) {
        int rr = i >> 5, cc = i & 31;
        if (r0 + rr < R)
            ((float4*)at[rr])[cc] = ((const float4*)(A + (size_t)(r0 + rr) * DIM))[cc];
    }
    __syncthreads();
    int c0 = (t & 31) * 4;
    int rb = (t >> 5) * 8;
    float accA[8][4], accB[8][4];
#pragma unroll
    for (int ee = 0; ee < 8; ee++)
#pragma unroll
        for (int j = 0; j < 4; j++) { accA[ee][j] = 0.f; accB[ee][j] = 0.f; }
    for (int k = 0; k < DIM; k += 4) {
        float4 wa0 = *(const float4*)&Wa[(k + 0) * DIM + c0];
        float4 wa1 = *(const float4*)&Wa[(k + 1) * DIM + c0];
        float4 wa2 = *(const float4*)&Wa[(k + 2) * DIM + c0];
        float4 wa3 = *(const float4*)&Wa[(k + 3) * DIM + c0];
        float4 wb0 = *(const float4*)&Wb[(k + 0) * DIM + c0];
        float4 wb1 = *(const float4*)&Wb[(k + 1) * DIM + c0];
        float4 wb2 = *(const float4*)&Wb[(k + 2) * DIM + c0];
        float4 wb3 = *(const float4*)&Wb[(k + 3) * DIM + c0];
#pragma unroll
        for (int ee = 0; ee < 8; ee++) {
            float4 a = *(float4*)&at[rb + ee][k];
            accA[ee][0] += a.x * wa0.x + a.y * wa1.x + a.z * wa2.x + a.w * wa3.x;
            accA[ee][1] += a.x * wa0.y + a.y * wa1.y + a.z * wa2.y + a.w * wa3.y;
            accA[ee][2] += a.x * wa0.z + a.y * wa1.z + a.z * wa2.z + a.w * wa3.z;
            accA[ee][3] += a.x * wa0.w + a.y * wa1.w + a.z * wa2.w + a.w * wa3.w;
            accB[ee][0] += a.x * wb0.x + a.y * wb1.x + a.z * wb2.x + a.w * wb3.x;
            accB[ee][1] += a.x * wb0.y + a.y * wb1.y + a.z * wb2.y + a.w * wb3.y;
            accB[ee][2] += a.x * wb0.z + a.y * wb1.z + a.z * wb2.z + a.w * wb3.z;
            accB[ee][3] += a.x * wb0.w + a.y * wb1.w + a.z * wb2.w + a.w * wb3.w;
        }
    }
    float4 bb = make_float4(0.f, 0.f, 0.f, 0.f);
    if (biasA) bb = *(const float4*)&biasA[c0];
#pragma unroll
    for (int ee = 0; ee < 8; ee++) {
        int r = r0 + rb + ee;
        if (r < R) {
            *(float4*)&outA[(size_t)r * DIM + c0] =
                make_float4(accA[ee][0] + bb.x, accA[ee][1] + bb.y,
                            accA[ee][2] + bb.z, accA[ee][3] + bb.w);
            *(float4*)&outB[(size_t)r * DIM + c0] =
                make_float4(accB[ee][0], accB[ee][1], accB[ee][2], accB[ee][3]);
        }
    }
}

// ---------------- node proj tile: h = x@Wn, + per-head att dots ----------------
__global__ __launch_bounds__(256) void node_proj_tile(
    const float* __restrict__ x, const float* __restrict__ W,
    const float* __restrict__ att_s, const float* __restrict__ att_d,
    float* __restrict__ h, float* __restrict__ ssrc, float* __restrict__ sdst, int N) {
    int r0 = blockIdx.x * 64, t = threadIdx.x;
    __shared__ float at[64][DIM];
    for (int i = t; i < 64 * 32; i += 256) {
        int rr = i >> 5, cc = i & 31;
        if (r0 + rr < N)
            ((float4*)at[rr])[cc] = ((const float4*)(x + (size_t)(r0 + rr) * DIM))[cc];
    }
    __syncthreads();
    int c0 = (t & 31) * 4;
    int rb = (t >> 5) * 8;
    float acc[8][4];
#pragma unroll
    for (int ee = 0; ee < 8; ee++)
        acc[ee][0] = acc[ee][1] = acc[ee][2] = acc[ee][3] = 0.f;
    for (int k = 0; k < DIM; k += 4) {
        float4 w0 = *(const float4*)&W[(k + 0) * DIM + c0];
        float4 w1 = *(const float4*)&W[(k + 1) * DIM + c0];
        float4 w2 = *(const float4*)&W[(k + 2) * DIM + c0];
        float4 w3 = *(const float4*)&W[(k + 3) * DIM + c0];
#pragma unroll
        for (int ee = 0; ee < 8; ee++) {
            float4 a = *(float4*)&at[rb + ee][k];
            acc[ee][0] += a.x * w0.x + a.y * w1.x + a.z * w2.x + a.w * w3.x;
            acc[ee][1] += a.x * w0.y + a.y * w1.y + a.z * w2.y + a.w * w3.y;
            acc[ee][2] += a.x * w0.z + a.y * w1.z + a.z * w2.z + a.w * w3.z;
            acc[ee][3] += a.x * w0.w + a.y * w1.w + a.z * w2.w + a.w * w3.w;
        }
    }
    int hh = (t & 31) >> 3;   // head owned by this col range
    float4 as = *(const float4*)&att_s[c0];
    float4 ad = *(const float4*)&att_d[c0];
#pragma unroll
    for (int ee = 0; ee < 8; ee++) {
        int r = r0 + rb + ee;
        if (r < N) {
            *(float4*)&h[(size_t)r * DIM + c0] =
                make_float4(acc[ee][0], acc[ee][1], acc[ee][2], acc[ee][3]);
            float ps = acc[ee][0]*as.x + acc[ee][1]*as.y + acc[ee][2]*as.z + acc[ee][3]*as.w;
            float pd = acc[ee][0]*ad.x + acc[ee][1]*ad.y + acc[ee][2]*ad.z + acc[ee][3]*ad.w;
#pragma unroll
            for (int mk = 1; mk < 8; mk <<= 1) {
                ps += __shfl_xor(ps, mk, 32);
                pd += __shfl_xor(pd, mk, 32);
            }
            if (((t & 31) & 7) == 0) {
                ssrc[r * HEADS + hh] = ps;
                sdst[r * HEADS + hh] = pd;
            }
        }
    }
}

// ---------------- layer kernels ----------------

// waE[k][h] = sum_c We[k][h*32+c] * att_edge[h*32+c]   (1 block, 128 threads)
__global__ void make_waE(const float* __restrict__ We, const float* __restrict__ att_e,
                         float* __restrict__ waE) {
    int k = threadIdx.x;
#pragma unroll
    for (int h = 0; h < HEADS; h++) {
        float s = 0.f;
#pragma unroll
        for (int c = 0; c < CH; c++) s += We[k * DIM + h * CH + c] * att_e[h * CH + c];
        waE[k * HEADS + h] = s;
    }
}

// standalone logits for layer 0 only.
__global__ void sedge_logits(const float* __restrict__ e, const float* __restrict__ waE,
                             const float* __restrict__ ssrc, const float* __restrict__ sdst,
                             const int* __restrict__ src, const int* __restrict__ dst,
                             float* __restrict__ lw, int E) {
    __shared__ float w[DIM * HEADS];
    int t = threadIdx.x;
    w[t] = waE[t]; w[t + 256] = waE[t + 256];
    __syncthreads();
    int g = t >> 5, lane = t & 31;
    int eid = blockIdx.x * 8 + g;
    if (eid >= E) return;
    const float* er = e + (size_t)eid * DIM;
    float s0 = 0.f, s1 = 0.f, s2 = 0.f, s3 = 0.f;
#pragma unroll
    for (int j = 0; j < 4; j++) {
        int k = lane + 32 * j;
        float v = er[k];
        s0 += v * w[k * 4 + 0]; s1 += v * w[k * 4 + 1];
        s2 += v * w[k * 4 + 2]; s3 += v * w[k * 4 + 3];
    }
#pragma unroll
    for (int m = 16; m; m >>= 1) {
        s0 += __shfl_xor(s0, m, 32); s1 += __shfl_xor(s1, m, 32);
        s2 += __shfl_xor(s2, m, 32); s3 += __shfl_xor(s3, m, 32);
    }
    if (lane == 0) {
        int sn = src[eid] * HEADS, dn = dst[eid] * HEADS;
        float l0 = ssrc[sn + 0] + sdst[dn + 0] + s0;
        float l1 = ssrc[sn + 1] + sdst[dn + 1] + s1;
        float l2 = ssrc[sn + 2] + sdst[dn + 2] + s2;
        float l3 = ssrc[sn + 3] + sdst[dn + 3] + s3;
        lw[eid * 4 + 0] = (l0 >= 0.f) ? l0 : 0.2f * l0;
        lw[eid * 4 + 1] = (l1 >= 0.f) ? l1 : 0.2f * l1;
        lw[eid * 4 + 2] = (l2 >= 0.f) ? l2 : 0.2f * l2;
        lw[eid * 4 + 3] = (l3 >= 0.f) ? l3 : 0.2f * l3;
    }
}

// per (node, head) thread: segment max, exp, sum. lw becomes unnormalized weights.
__global__ void seg_softmax(const int* __restrict__ off, const int* __restrict__ csr,
                            float* __restrict__ lw, float* __restrict__ den, int NH) {
    int i = blockIdx.x * blockDim.x + threadIdx.x;
    if (i >= NH) return;
    int n = i >> 2, hh = i & 3;
    int o0 = off[n], o1 = off[n + 1];
    float m = -1e30f;
    for (int o = o0; o < o1; o++) m = fmaxf(m, lw[csr[o] * HEADS + hh]);
    float s = 0.f;
    for (int o = o0; o < o1; o++) {
        int idx = csr[o] * HEADS + hh;
        float w = __expf(lw[idx] - m);
        lw[idx] = w;
        s += w;
    }
    den[i] = s;
}

// conv gather, 4-way edge-parallel per node. 512 thr = 4 parts x 128 cols.
__global__ __launch_bounds__(512) void conv_ln4(
    const int* __restrict__ off, const int* __restrict__ csr, const int* __restrict__ src,
    const float* __restrict__ lw, const float* __restrict__ den,
    const float* __restrict__ hbuf, const float* __restrict__ e, const float* __restrict__ We,
    const float* __restrict__ bn, const float* __restrict__ g, const float* __restrict__ b,
    float* __restrict__ x, int N) {
    int t = threadIdx.x;
    int tt = t & 127, part = t >> 7;
    int n = blockIdx.x;
    int hh = tt >> 5;
    __shared__ float aggeP[4][HEADS][DIM];
    __shared__ float acchP[4][DIM];
    __shared__ float ehcP[4][DIM];
    __shared__ float wred[16];
    int o0 = off[n], o1 = off[n + 1];
    float acch = 0.f, a0 = 0.f, a1 = 0.f, a2 = 0.f, a3 = 0.f;
    for (int o = o0 + part; o < o1; o += 4) {
        int eid = csr[o];
        int s = src[eid];
        float4 al = *(const float4*)&lw[eid * 4];
        acch += ((&al.x)[hh]) * hbuf[(size_t)s * DIM + tt];
        float ev = e[(size_t)eid * DIM + tt];
        a0 += al.x * ev; a1 += al.y * ev; a2 += al.z * ev; a3 += al.w * ev;
    }
    aggeP[part][0][tt] = a0; aggeP[part][1][tt] = a1;
    aggeP[part][2][tt] = a2; aggeP[part][3][tt] = a3;
    acchP[part][tt] = acch;
    __syncthreads();
    float ehc = 0.f;
    int k0 = part * 32;
    for (int k = k0; k < k0 + 32; k++) {
        float ag = aggeP[0][hh][k] + aggeP[1][hh][k] + aggeP[2][hh][k] + aggeP[3][hh][k];
        ehc += ag * We[k * DIM + tt];
    }
    ehcP[part][tt] = ehc;
    __syncthreads();
    float conv = (acchP[0][tt] + acchP[1][tt] + acchP[2][tt] + acchP[3][tt]
                + ehcP[0][tt] + ehcP[1][tt] + ehcP[2][tt] + ehcP[3][tt])
                 / (den[n * HEADS + hh] + 1e-16f) + bn[tt];
    int w = t >> 6;
    float s1 = conv;
#pragma unroll
    for (int mk = 32; mk; mk >>= 1) s1 += __shfl_xor(s1, mk, 64);
    if ((t & 63) == 0) wred[w] = s1;
    __syncthreads();
    float mu = (wred[w] + wred[w ^ 1]) * (1.f / DIM);
    float diff = conv - mu;
    float s2 = diff * diff;
#pragma unroll
    for (int mk = 32; mk; mk >>= 1) s2 += __shfl_xor(s2, mk, 64);
    if ((t & 63) == 0) wred[8 + w] = s2;
    __syncthreads();
    float var = (wred[8 + w] + wred[8 + (w ^ 1)]) * (1.f / DIM);
    if (part == 0) {
        float y = diff * rsqrtf(var + 1e-5f) * g[tt] + b[tt];
        x[(size_t)n * DIM + tt] = fmaxf(y, 0.f) + x[(size_t)n * DIM + tt];
    }
}

// flash-style cross attention: 64 queries x 1 batch per block, 256 thr = 64q x 4h.
__global__ __launch_bounds__(256) void cross_attn_tile(
    float* __restrict__ x, const float* __restrict__ qg,
    const float* __restrict__ kb, const float* __restrict__ vb,
    const float* __restrict__ Wo, const float* __restrict__ g,
    const float* __restrict__ b, const int* __restrict__ boff) {
    int bb = blockIdx.y;
    int n0 = boff[bb] + blockIdx.x * 64;
    int cnt = boff[bb + 1] - n0;
    if (cnt <= 0) return;
    int nq = min(64, cnt);
    int t = threadIdx.x;
    int q = t & 63, h = t >> 6;

    __shared__ float smem[64 * 132];

    float qv[32];
    if (q < nq) {
        const float4* qp = (const float4*)(qg + (size_t)(n0 + q) * DIM + h * CH);
#pragma unroll
        for (int j = 0; j < 8; j++) {
            float4 v = qp[j];
            qv[4*j+0] = v.x; qv[4*j+1] = v.y; qv[4*j+2] = v.z; qv[4*j+3] = v.w;
        }
    } else {
#pragma unroll
        for (int c = 0; c < 32; c++) qv[c] = 0.f;
    }

    float oacc[32];
#pragma unroll
    for (int c = 0; c < 32; c++) oacc[c] = 0.f;
    float m = -1e30f, l = 0.f;

    const float4* Ksrc = (const float4*)(kb + (size_t)bb * MEMLEN * DIM);
    const float4* Vsrc = (const float4*)(vb + (size_t)bb * MEMLEN * DIM);
    float4* Kl = (float4*)smem;
    float4* Vl = (float4*)(smem + 32 * DIM);

    for (int ch = 0; ch < MEMLEN / 32; ch++) {
        __syncthreads();
#pragma unroll
        for (int r = 0; r < 4; r++) {
            int idx = t + r * 256;
            Kl[idx] = Ksrc[ch * 1024 + idx];
            Vl[idx] = Vsrc[ch * 1024 + idx];
        }
        __syncthreads();
        float sc[32];
#pragma unroll
        for (int kk = 0; kk < 32; kk++) {
            const float* kp = smem + kk * DIM + h * CH;
            float s = 0.f;
#pragma unroll
            for (int c = 0; c < 32; c++) s += qv[c] * kp[c];
            sc[kk] = s * 0.17677669529663689f;
        }
        float mc = sc[0];
#pragma unroll
        for (int kk = 1; kk < 32; kk++) mc = fmaxf(mc, sc[kk]);
        float mn = fmaxf(m, mc);
        float scale = __expf(m - mn);
        m = mn;
        float ls = 0.f;
#pragma unroll
        for (int kk = 0; kk < 32; kk++) {
            float w = __expf(sc[kk] - mn);
            sc[kk] = w;
            ls += w;
        }
        l = l * scale + ls;
#pragma unroll
        for (int c = 0; c < 32; c++) oacc[c] *= scale;
#pragma unroll
        for (int kk = 0; kk < 32; kk++) {
            const float* vp = smem + 32 * DIM + kk * DIM + h * CH;
            float w = sc[kk];
#pragma unroll
            for (int c = 0; c < 32; c++) oacc[c] += w * vp[c];
        }
    }
    __syncthreads();
    {
        float inv = 1.f / l;
        float* ap = smem + q * 132 + h * CH;
#pragma unroll
        for (int c = 0; c < 32; c++) ap[c] = oacc[c] * inv;
    }
    __syncthreads();
    int c0 = (t & 31) * 4;
    int rb = (t >> 5) * 8;
    float acc2[8][4];
#pragma unroll
    for (int ee = 0; ee < 8; ee++)
        acc2[ee][0] = acc2[ee][1] = acc2[ee][2] = acc2[ee][3] = 0.f;
    for (int k = 0; k < DIM; k += 4) {
        float4 w0 = *(const float4*)&Wo[(k + 0) * DIM + c0];
        float4 w1 = *(const float4*)&Wo[(k + 1) * DIM + c0];
        float4 w2 = *(const float4*)&Wo[(k + 2) * DIM + c0];
        float4 w3 = *(const float4*)&Wo[(k + 3) * DIM + c0];
#pragma unroll
        for (int ee = 0; ee < 8; ee++) {
            float4 a = *(const float4*)(smem + (rb + ee) * 132 + k);
            acc2[ee][0] += a.x * w0.x + a.y * w1.x + a.z * w2.x + a.w * w3.x;
            acc2[ee][1] += a.x * w0.y + a.y * w1.y + a.z * w2.y + a.w * w3.y;
            acc2[ee][2] += a.x * w0.z + a.y * w1.z + a.z * w2.z + a.w * w3.z;
            acc2[ee][3] += a.x * w0.w + a.y * w1.w + a.z * w2.w + a.w * w3.w;
        }
    }
    float4 gg = *(const float4*)&g[c0];
    float4 bb4 = *(const float4*)&b[c0];
#pragma unroll
    for (int ee = 0; ee < 8; ee++) {
        int r = rb + ee;
        if (r < nq) {
            float4 xr = *(const float4*)&x[(size_t)(n0 + r) * DIM + c0];
            float o0 = acc2[ee][0] + xr.x, o1 = acc2[ee][1] + xr.y;
            float o2 = acc2[ee][2] + xr.z, o3 = acc2[ee][3] + xr.w;
            float s1 = o0 + o1 + o2 + o3;
#pragma unroll
            for (int mk = 16; mk; mk >>= 1) s1 += __shfl_xor(s1, mk, 32);
            float mu = s1 * (1.f / DIM);
            float d0 = o0 - mu, d1 = o1 - mu, d2 = o2 - mu, d3 = o3 - mu;
            float s2 = d0*d0 + d1*d1 + d2*d2 + d3*d3;
#pragma unroll
            for (int mk = 16; mk; mk >>= 1) s2 += __shfl_xor(s2, mk, 32);
            float rs = rsqrtf(s2 * (1.f / DIM) + 1e-5f);
            float4 o = make_float4(fmaxf(d0 * rs * gg.x + bb4.x, 0.f),
                                   fmaxf(d1 * rs * gg.y + bb4.y, 0.f),
                                   fmaxf(d2 * rs * gg.z + bb4.z, 0.f),
                                   fmaxf(d3 * rs * gg.w + bb4.w, 0.f));
            *(float4*)&x[(size_t)(n0 + r) * DIM + c0] = o;
        }
    }
}

// ---------------- MFMA edge MLP v8 (race-fixed, T14, fused next-layer logits) ----------------
// launch_bounds MUST stay (256,2): tighter caps spill catastrophically (R10/R14).
// Bulk B preload (R15) beats 1-deep prefetch (R16): loads schedule under staging.
__global__ __launch_bounds__(256, 2) void edge_mlp_mfma(
    float* __restrict__ e, const float* __restrict__ xs, const float* __restrict__ xd,
    const int* __restrict__ src, const int* __restrict__ dst,
    const ushort* __restrict__ W1f,   // [12 ks][8 ct][64 lane][8 j] bf16
    const ushort* __restrict__ W2f,   // [8 ks][8 ct][64 lane][8 j] bf16
    const float* __restrict__ Eb2,
    const float* __restrict__ waE,    // [128][4], next layer (or null)
    const float* __restrict__ ssrc, const float* __restrict__ sdst,
    float* __restrict__ lw, int doLogits, int E) {
    __shared__ __align__(16) char smemraw[64 * 132 * 4];  // As (bf16) then Af (fp32 padded)
    ushort* As = (ushort*)smemraw;
    float*  Af = (float*)smemraw;
    __shared__ float waEl[DIM * HEADS];
    int t = threadIdx.x;
    int e0 = blockIdx.x * 64;

    if (doLogits) {
        waEl[t] = waE[t];
        waEl[t + 256] = waE[t + 256];
    }

    int l = t & 63, wid = t >> 6;
    int g = l >> 4;
    int lr = l & 15;
    int ct0 = 2 * wid, ct1 = 2 * wid + 1;
    int col0 = lr + 16 * ct0, col1 = lr + 16 * ct1;

    // T14 early-issue: xs/xd gathers overlap staging + phase-1 MFMAs
    float xsd0[16], xsd1[16];
#pragma unroll
    for (int r = 0; r < 4; r++) {
#pragma unroll
        for (int j = 0; j < 4; j++) {
            int grow = e0 + r * 16 + g * 4 + j;
            int idx = r * 4 + j;
            if (grow < E) {
                int s = src[grow], d = dst[grow];
                xsd0[idx] = xs[(size_t)s * DIM + col0] + xd[(size_t)d * DIM + col0];
                xsd1[idx] = xs[(size_t)s * DIM + col1] + xd[(size_t)d * DIM + col1];
            } else {
                xsd0[idx] = 0.f; xsd1[idx] = 0.f;
            }
        }
    }

    // stage e-tile -> bf16 hi (k 0..127) + lo (k 128..255), swizzled
#pragma unroll
    for (int it = 0; it < 8; it++) {
        int i = t + it * 256;
        int row = i >> 5, c4 = i & 31;
        float4 v;
        if (e0 + row < E) v = *(const float4*)&e[(size_t)(e0 + row) * DIM + c4 * 4];
        else v = make_float4(0.f, 0.f, 0.f, 0.f);
        ushort h0, l0, h1, l1, h2, l2, h3, l3;
        split_bf(v.x, h0, l0); split_bf(v.y, h1, l1);
        split_bf(v.z, h2, l2); split_bf(v.w, h3, l3);
        int k = c4 * 4;
        int off = k & 7;
        int kbh = (k >> 3) ^ (row & 7);
        int kbl = ((128 + k) >> 3) ^ (row & 7);
        uint2 hw, lw2;
        hw.x = (uint)h0 | ((uint)h1 << 16); hw.y = (uint)h2 | ((uint)h3 << 16);
        lw2.x = (uint)l0 | ((uint)l1 << 16); lw2.y = (uint)l2 | ((uint)l3 << 16);
        *(uint2*)&As[row * 256 + kbh * 8 + off] = hw;
        *(uint2*)&As[row * 256 + kbl * 8 + off] = lw2;
    }

    // phase-1 B fragments in registers (L2-hot)
    bf16x8 b1[12][2];
#pragma unroll
    for (int ks = 0; ks < 12; ks++) {
        b1[ks][0] = *(const bf16x8*)&W1f[(size_t)ks * 4096 + ct0 * 512 + l * 8];
        b1[ks][1] = *(const bf16x8*)&W1f[(size_t)ks * 4096 + ct1 * 512 + l * 8];
    }

    __syncthreads();   // A staged (+ waEl)

    f32x4 acc[4][2];
#pragma unroll
    for (int r = 0; r < 4; r++) {
        acc[r][0] = (f32x4){0.f, 0.f, 0.f, 0.f};
        acc[r][1] = (f32x4){0.f, 0.f, 0.f, 0.f};
    }

    // phase 1: K = 384
#pragma unroll
    for (int ks = 0; ks < 12; ks++) {
        int ksA = (ks < 8) ? ks : (ks - 8);
#pragma unroll
        for (int r = 0; r < 4; r++) {
            int arow = r * 16 + lr;
            int kbm = (ksA * 4 + g) ^ (arow & 7);
            bf16x8 af = *(bf16x8*)&As[arow * 256 + kbm * 8];
            acc[r][0] = __builtin_amdgcn_mfma_f32_16x16x32_bf16(af, b1[ks][0], acc[r][0], 0, 0, 0);
            acc[r][1] = __builtin_amdgcn_mfma_f32_16x16x32_bf16(af, b1[ks][1], acc[r][1], 0, 0, 0);
        }
    }

    // phase-2 B fragments
    bf16x8 b2f[8][2];
#pragma unroll
    for (int ks = 0; ks < 8; ks++) {
        b2f[ks][0] = *(const bf16x8*)&W2f[(size_t)ks * 4096 + ct0 * 512 + l * 8];
        b2f[ks][1] = *(const bf16x8*)&W2f[(size_t)ks * 4096 + ct1 * 512 + l * 8];
    }

    __syncthreads();   // RACE FIX: all waves' phase-1 As reads complete before hid writes

    // phase-1 epilogue: + xsd (preloaded), relu, split -> hid into As
    int kb0 = col0 >> 2, off0 = (2 * col0) & 7;
    int kb1 = col1 >> 2, off1 = (2 * col1) & 7;
#pragma unroll
    for (int r = 0; r < 4; r++) {
#pragma unroll
        for (int j = 0; j < 4; j++) {
            int rowloc = r * 16 + g * 4 + j;
            float v0 = fmaxf(acc[r][0][j] + xsd0[r * 4 + j], 0.f);
            float v1 = fmaxf(acc[r][1][j] + xsd1[r * 4 + j], 0.f);
            ushort h0s, l0s, h1s, l1s;
            split_bf(v0, h0s, l0s);
            split_bf(v1, h1s, l1s);
            int rs = rowloc & 7;
            *(uint*)&As[rowloc * 256 + (kb0 ^ rs) * 8 + off0] = (uint)h0s | ((uint)l0s << 16);
            *(uint*)&As[rowloc * 256 + (kb1 ^ rs) * 8 + off1] = (uint)h1s | ((uint)l1s << 16);
        }
    }
    __syncthreads();   // hid complete across all waves

    // phase 2: K = 256
    f32x4 acc2[4][2];
#pragma unroll
    for (int r = 0; r < 4; r++) {
        acc2[r][0] = (f32x4){0.f, 0.f, 0.f, 0.f};
        acc2[r][1] = (f32x4){0.f, 0.f, 0.f, 0.f};
    }
#pragma unroll
    for (int ks = 0; ks < 8; ks++) {
#pragma unroll
        for (int r = 0; r < 4; r++) {
            int arow = r * 16 + lr;
            int kbm = (ks * 4 + g) ^ (arow & 7);
            bf16x8 af = *(bf16x8*)&As[arow * 256 + kbm * 8];
            acc2[r][0] = __builtin_amdgcn_mfma_f32_16x16x32_bf16(af, b2f[ks][0], acc2[r][0], 0, 0, 0);
            acc2[r][1] = __builtin_amdgcn_mfma_f32_16x16x32_bf16(af, b2f[ks][1], acc2[r][1], 0, 0, 0);
        }
    }
    __syncthreads();   // hid reads done; As dead -> reuse as Af[64][132]

    // epilogue 2a: Af = acc2 + Eb2
    float b20 = Eb2[col0], b21 = Eb2[col1];
#pragma unroll
    for (int r = 0; r < 4; r++) {
#pragma unroll
        for (int j = 0; j < 4; j++) {
            int rowloc = r * 16 + g * 4 + j;
            Af[rowloc * 132 + col0] = acc2[r][0][j] + b20;
            Af[rowloc * 132 + col1] = acc2[r][1][j] + b21;
        }
    }
    __syncthreads();

    // epilogue 2b: coalesced float4 RMW of e; save final values back into Af
#pragma unroll
    for (int it = 0; it < 8; it++) {
        int i = t + it * 256;
        int row = i >> 5, c4 = i & 31;
        int grow = e0 + row;
        if (grow < E) {
            float4 ev = *(const float4*)&e[(size_t)grow * DIM + c4 * 4];
            float* ap = &Af[row * 132 + c4 * 4];
            ev.x += ap[0]; ev.y += ap[1]; ev.z += ap[2]; ev.w += ap[3];
            *(float4*)&e[(size_t)grow * DIM + c4 * 4] = ev;
            ap[0] = ev.x; ap[1] = ev.y; ap[2] = ev.z; ap[3] = ev.w;
        }
    }

    // fused next-layer logits (raw leaky logits; seg_softmax normalizes later)
    if (doLogits) {
        __syncthreads();
        int row = t >> 2, h = t & 3;
        int grow = e0 + row;
        if (grow < E) {
            const float* ar = &Af[row * 132];
            float s = 0.f;
#pragma unroll 8
            for (int k = 0; k < DIM; k++) s += ar[k] * waEl[k * 4 + h];
            s += ssrc[src[grow] * HEADS + h] + sdst[dst[grow] * HEADS + h];
            lw[grow * 4 + h] = (s >= 0.f) ? s : 0.2f * s;
        }
    }
}

// ---------------- driver ----------------

extern "C" void kernel_launch(void* const* d_in, const int* in_sizes, int n_in,
                              void* d_out, int out_size, void* d_ws, size_t ws_size,
                              hipStream_t stream) {
    const float* node_feats = (const float*)d_in[0];
    const float* edge_feats = (const float*)d_in[1];
    const float* memory     = (const float*)d_in[2];
    const float* Wn   = (const float*)d_in[3];
    const float* bn   = (const float*)d_in[4];
    const float* We   = (const float*)d_in[5];
    const float* att_src  = (const float*)d_in[6];
    const float* att_dst  = (const float*)d_in[7];
    const float* att_edge = (const float*)d_in[8];
    const float* ln1_g = (const float*)d_in[9];
    const float* ln1_b = (const float*)d_in[10];
    const float* ln2_g = (const float*)d_in[11];
    const float* ln2_b = (const float*)d_in[12];
    const float* Wq = (const float*)d_in[13];
    const float* Wk = (const float*)d_in[14];
    const float* Wv = (const float*)d_in[15];
    const float* Wo = (const float*)d_in[16];
    const float* Ew1 = (const float*)d_in[17];
    const float* Eb1 = (const float*)d_in[18];
    const float* Ew2 = (const float*)d_in[19];
    const float* Eb2 = (const float*)d_in[20];
    const int* edge_index = (const int*)d_in[21];
    const int* node2batch = (const int*)d_in[22];

    const int N = in_sizes[0] / DIM;
    const int E = in_sizes[1] / DIM;
    const int Bn = in_sizes[2] / (MEMLEN * DIM);
    const int* srcA = edge_index;
    const int* dstA = edge_index + E;

    float* x = (float*)d_out;
    float* e = x + (size_t)N * DIM;

    // workspace carve
    char* p = (char*)d_ws;
    auto carve = [&](size_t bytes) {
        void* r = (void*)p;
        p += (bytes + 255) & ~(size_t)255;
        return r;
    };
    float* h     = (float*)carve((size_t)N * DIM * 4);
    float* qg    = (float*)carve((size_t)N * DIM * 4);
    float* xs    = (float*)carve((size_t)N * DIM * 4);
    float* xd    = (float*)carve((size_t)N * DIM * 4);
    float* ssrc  = (float*)carve((size_t)N * HEADS * 4);
    float* sdst  = (float*)carve((size_t)N * HEADS * 4);
    float* lw    = (float*)carve((size_t)E * HEADS * 4);
    float* den   = (float*)carve((size_t)N * HEADS * 4);
    float* waE   = (float*)carve((size_t)DIM * HEADS * 4);
    float* kbuf  = (float*)carve((size_t)Bn * MEMLEN * DIM * 4);
    float* vbuf  = (float*)carve((size_t)Bn * MEMLEN * DIM * 4);
    ushort* W1f  = (ushort*)carve((size_t)LAYERS * 12 * 4096 * 2);
    ushort* W2f  = (ushort*)carve((size_t)LAYERS * 8 * 4096 * 2);
    int* deg     = (int*)carve((size_t)N * 4);
    int* cur     = (int*)carve((size_t)N * 4);
    int* off     = (int*)carve(((size_t)N + 1) * 4);
    int* csr     = (int*)carve((size_t)E * 4);
    int* bcnt    = (int*)carve((size_t)Bn * 4);
    int* boff    = (int*)carve(((size_t)Bn + 1) * 4);

    // init outputs from inputs
    {
        long nx = (long)N * DIM / 4;
        copy_f4<<<dim3(2048), dim3(256), 0, stream>>>((const float4*)node_feats, (float4*)x, nx);
        long nen = (long)E * DIM / 4;
        copy_f4<<<dim3(4096), dim3(256), 0, stream>>>((const float4*)edge_feats, (float4*)e, nen);
    }

    // bf16 fragment-order weights (all layers, once)
    make_w1f<<<dim3((LAYERS * 49152 + 255) / 256), dim3(256), 0, stream>>>(Ew1, W1f);
    make_w2f<<<dim3((LAYERS * 32768 + 255) / 256), dim3(256), 0, stream>>>(Ew2, W2f);

    // CSR over dst + per-batch node offsets
    hipMemsetAsync(deg, 0, (size_t)N * 4, stream);
    hipMemsetAsync(cur, 0, (size_t)N * 4, stream);
    hipMemsetAsync(bcnt, 0, (size_t)Bn * 4, stream);
    hist_k<<<dim3((E + 255) / 256), dim3(256), 0, stream>>>(dstA, E, deg);
    csr_offsets<<<dim3(1), dim3(1024), 0, stream>>>(deg, N, off);
    csr_fill<<<dim3((E + 255) / 256), dim3(256), 0, stream>>>(dstA, E, off, cur, csr);
    hist_k<<<dim3((N + 255) / 256), dim3(256), 0, stream>>>(node2batch, N, bcnt);
    csr_offsets<<<dim3(1), dim3(1024), 0, stream>>>(bcnt, Bn, boff);

    const int mrows = Bn * MEMLEN;
    const int maxTiles = 1024 / 64;  // MAX_NODE / 64

    // layer-0 logits (standalone): needs node_proj(0) + waE(0)
    node_proj_tile<<<dim3((N + 63) / 64), dim3(256), 0, stream>>>(
        x, Wn, att_src, att_dst, h, ssrc, sdst, N);
    make_waE<<<dim3(1), dim3(DIM), 0, stream>>>(We, att_edge, waE);
    sedge_logits<<<dim3((E + 7) / 8), dim3(256), 0, stream>>>(
        e, waE, ssrc, sdst, srcA, dstA, lw, E);

    for (int l = 0; l < LAYERS; l++) {
        const float* We_l  = We  + (size_t)l * DIM * DIM;
        const float* Wq_l  = Wq  + (size_t)l * DIM * DIM;
        const float* Wo_l  = Wo  + (size_t)l * DIM * DIM;
        const float* Wk_l  = Wk  + (size_t)l * DIM * DIM;
        const float* Wv_l  = Wv  + (size_t)l * DIM * DIM;
        const float* Ew1_l = Ew1 + (size_t)l * 3 * DIM * DIM;

        seg_softmax<<<dim3((N * HEADS + 255) / 256), dim3(256), 0, stream>>>(
            off, csr, lw, den, N * HEADS);
        conv_ln4<<<dim3(N), dim3(512), 0, stream>>>(
            off, csr, srcA, lw, den, h, e, We_l,
            bn + l * DIM, ln1_g + l * DIM, ln1_b + l * DIM, x, N);
        gemm128_dual<<<dim3((mrows + 63) / 64), dim3(256), 0, stream>>>(
            memory, Wk_l, Wv_l, nullptr, kbuf, vbuf, mrows);
        gemm128<<<dim3((N + 63) / 64), dim3(256), 0, stream>>>(
            x, Wq_l, nullptr, qg, N);
        cross_attn_tile<<<dim3(maxTiles, Bn), dim3(256), 0, stream>>>(
            x, qg, kbuf, vbuf, Wo_l, ln2_g + l * DIM, ln2_b + l * DIM, boff);
        gemm128_dual<<<dim3((N + 63) / 64), dim3(256), 0, stream>>>(
            x, Ew1_l + (size_t)DIM * DIM, Ew1_l + (size_t)2 * DIM * DIM,
            Eb1 + l * DIM, xs, xd, N);

        if (l + 1 < LAYERS) {
            node_proj_tile<<<dim3((N + 63) / 64), dim3(256), 0, stream>>>(
                x, Wn + (size_t)(l + 1) * DIM * DIM,
                att_src + (l + 1) * DIM, att_dst + (l + 1) * DIM, h, ssrc, sdst, N);
            make_waE<<<dim3(1), dim3(DIM), 0, stream>>>(
                We + (size_t)(l + 1) * DIM * DIM, att_edge + (l + 1) * DIM, waE);
            edge_mlp_mfma<<<dim3((E + 63) / 64), dim3(256), 0, stream>>>(
                e, xs, xd, srcA, dstA,
                W1f + (size_t)l * 12 * 4096, W2f + (size_t)l * 8 * 4096,
                Eb2 + l * DIM, waE, ssrc, sdst, lw, 1, E);
        } else {
            edge_mlp_mfma<<<dim3((E + 63) / 64), dim3(256), 0, stream>>>(
                e, xs, xd, srcA, dstA,
                W1f + (size_t)l * 12 * 4096, W2f + (size_t)l * 8 * 4096,
                Eb2 + l * DIM, nullptr, nullptr, nullptr, nullptr, 0, E);
        }
    }
}